// Round 7
// baseline (1668.763 us; speedup 1.0000x reference)
//
#include <hip/hip_runtime.h>

#define N_NODES 50000
#define N_EDGES 1250000
#define HID 64
#define N_LAYERS 3
#define N_GRAPHS 64
#define EPS 1e-5f

// ---- dst-bucketed edge binning ----
#define BK_SHIFT 5
#define BK_NODES 32                                    // nodes per bucket
#define N_BUCKETS ((N_NODES + BK_NODES - 1) / BK_NODES) // 1563
#define BK_CAP 1024                                    // slots/bucket (mean 800, +7.9 sigma)

#define FB_THREADS 1024
#define FB_EPT 8
#define FB_EPB (FB_THREADS * FB_EPT)                   // 8192
#define FB_BLOCKS ((N_EDGES + FB_EPB - 1) / FB_EPB)    // 153

// ------ m = h @ W ; optional row gather via xidx (fuses embedding layer) ----
__global__ __launch_bounds__(256) void k_linear(const float* __restrict__ h,
                                                const int* __restrict__ xidx,
                                                const float* __restrict__ W,
                                                float* __restrict__ m) {
    __shared__ float Wl[HID * HID];   // 16 KB
    __shared__ float hl[4 * HID];
    int tid = threadIdx.x;
    for (int k = tid; k < HID * HID; k += 256) Wl[k] = W[k];
    int row0 = blockIdx.x * 4;        // 50000 % 4 == 0 -> exact
    {
        int rr = row0 + (tid >> 6);
        int srcrow = xidx ? xidx[rr] : rr;
        hl[tid] = h[srcrow * HID + (tid & 63)];
    }
    __syncthreads();
    int r = tid >> 6, c = tid & 63;
    float acc = 0.f;
#pragma unroll
    for (int k = 0; k < HID; ++k) acc += hl[r * HID + k] * Wl[k * HID + c];
    m[(row0 + r) * HID + c] = acc;
}

// ---- bin edges into dst-buckets: entry = ((dstLocal<<16)|src, w_bits) ------
// per-block LDS histogram -> one global reservation per (block,bucket) ->
// scatter into per-block-contiguous runs (write-amplification killer)
__global__ __launch_bounds__(FB_THREADS) void k_bucket(const int* __restrict__ src,
                                                       const int* __restrict__ dst,
                                                       const float* __restrict__ w,
                                                       int* __restrict__ gcnt,
                                                       int2* __restrict__ buf) {
    __shared__ int histA[N_BUCKETS];   // pass A: counts; then block base
    __shared__ int curB[N_BUCKETS];    // pass B: local cursor
    int t = threadIdx.x;
    for (int k = t; k < N_BUCKETS; k += FB_THREADS) { histA[k] = 0; curB[k] = 0; }
    __syncthreads();
    int e0 = blockIdx.x * FB_EPB;
#pragma unroll
    for (int q = 0; q < FB_EPT; ++q) {
        int e = e0 + q * FB_THREADS + t;
        if (e < N_EDGES) atomicAdd(&histA[dst[e] >> BK_SHIFT], 1);
    }
    __syncthreads();
    for (int k = t; k < N_BUCKETS; k += FB_THREADS) {
        int c = histA[k];
        histA[k] = c ? atomicAdd(&gcnt[k], c) : 0;   // reserve block range
    }
    __syncthreads();
#pragma unroll
    for (int q = 0; q < FB_EPT; ++q) {
        int e = e0 + q * FB_THREADS + t;
        if (e < N_EDGES) {
            int d = dst[e];
            int b = d >> BK_SHIFT;
            int r = atomicAdd(&curB[b], 1);
            int pos = (b << 10) + histA[b] + r;       // BK_CAP == 1024
            buf[pos] = make_int2(((d & (BK_NODES - 1)) << 16) | src[e],
                                 __float_as_int(w[e]));
        }
    }
}

// ---- per-bucket aggregate in LDS + bias + LayerNorm + ReLU -----------------
// block = 1 bucket (32 nodes); 4 waves; lane = channel; 8-deep gather pipeline
__global__ __launch_bounds__(256) void k_agg(const float* __restrict__ m,
                                             const int2* __restrict__ buf,
                                             const int* __restrict__ gcnt,
                                             const float* __restrict__ bias,
                                             const float* __restrict__ g,
                                             const float* __restrict__ b,
                                             float* __restrict__ hout) {
    __shared__ float acc[BK_NODES * HID];   // 8 KB
    int bkt = blockIdx.x;
    int t = threadIdx.x;
    int lane = t & 63, wv = t >> 6;
    for (int k = t; k < BK_NODES * HID; k += 256) acc[k] = 0.f;
    __syncthreads();
    int cnt = gcnt[bkt];
    const int2* ebase = buf + (bkt << 10);
    int last = cnt - 1;
    for (int i = wv; i < cnt; i += 32) {    // wave wv owns i, i+4, ..., i+28
        int2 e0 = ebase[min(i +  0, last)];
        int2 e1 = ebase[min(i +  4, last)];
        int2 e2 = ebase[min(i +  8, last)];
        int2 e3 = ebase[min(i + 12, last)];
        int2 e4 = ebase[min(i + 16, last)];
        int2 e5 = ebase[min(i + 20, last)];
        int2 e6 = ebase[min(i + 24, last)];
        int2 e7 = ebase[min(i + 28, last)];
        float w0 = (i +  0 <= last) ? __int_as_float(e0.y) : 0.f;
        float w1 = (i +  4 <= last) ? __int_as_float(e1.y) : 0.f;
        float w2 = (i +  8 <= last) ? __int_as_float(e2.y) : 0.f;
        float w3 = (i + 12 <= last) ? __int_as_float(e3.y) : 0.f;
        float w4 = (i + 16 <= last) ? __int_as_float(e4.y) : 0.f;
        float w5 = (i + 20 <= last) ? __int_as_float(e5.y) : 0.f;
        float w6 = (i + 24 <= last) ? __int_as_float(e6.y) : 0.f;
        float w7 = (i + 28 <= last) ? __int_as_float(e7.y) : 0.f;
        // 8 independent gathers in flight
        float v0 = m[(e0.x & 0xFFFF) * HID + lane] * w0;
        float v1 = m[(e1.x & 0xFFFF) * HID + lane] * w1;
        float v2 = m[(e2.x & 0xFFFF) * HID + lane] * w2;
        float v3 = m[(e3.x & 0xFFFF) * HID + lane] * w3;
        float v4 = m[(e4.x & 0xFFFF) * HID + lane] * w4;
        float v5 = m[(e5.x & 0xFFFF) * HID + lane] * w5;
        float v6 = m[(e6.x & 0xFFFF) * HID + lane] * w6;
        float v7 = m[(e7.x & 0xFFFF) * HID + lane] * w7;
        atomicAdd(&acc[((e0.x >> 16) << 6) + lane], v0);
        atomicAdd(&acc[((e1.x >> 16) << 6) + lane], v1);
        atomicAdd(&acc[((e2.x >> 16) << 6) + lane], v2);
        atomicAdd(&acc[((e3.x >> 16) << 6) + lane], v3);
        atomicAdd(&acc[((e4.x >> 16) << 6) + lane], v4);
        atomicAdd(&acc[((e5.x >> 16) << 6) + lane], v5);
        atomicAdd(&acc[((e6.x >> 16) << 6) + lane], v6);
        atomicAdd(&acc[((e7.x >> 16) << 6) + lane], v7);
    }
    __syncthreads();
    // bias + LN + ReLU for this bucket's 32 nodes (8 per wave)
    int gbase = bkt * BK_NODES;
#pragma unroll
    for (int q = 0; q < 8; ++q) {
        int n = wv * 8 + q;
        int gn = gbase + n;
        if (gn < N_NODES) {
            float v = acc[(n << 6) + lane] + bias[lane];
            float s = v;
#pragma unroll
            for (int off = 32; off; off >>= 1) s += __shfl_xor(s, off, 64);
            float mu = s * (1.f / 64.f);
            float dd = v - mu;
            float vv = dd * dd;
#pragma unroll
            for (int off = 32; off; off >>= 1) vv += __shfl_xor(vv, off, 64);
            float var = vv * (1.f / 64.f);
            float y = dd * rsqrtf(var + EPS) * g[lane] + b[lane];
            hout[gn * HID + lane] = fmaxf(y, 0.f);
        }
    }
}

// ---- misc: graph bounds (batch sorted) + zero pooling scratch --------------
__global__ __launch_bounds__(256) void k_misc(const int* __restrict__ batch,
                                              int* __restrict__ start,
                                              float* __restrict__ sums,
                                              unsigned* __restrict__ maxs) {
    int t = threadIdx.x;
    if (t <= N_GRAPHS) {
        int lo = 0, hi = N_NODES;
        while (lo < hi) {
            int mid = (lo + hi) >> 1;
            if (batch[mid] < t) lo = mid + 1; else hi = mid;
        }
        start[t] = lo;
    }
    for (int k = t; k < N_GRAPHS * HID; k += 256) {
        sums[k] = 0.f;
        maxs[k] = 0u;
    }
}

// ---------------- pooling: sliced segmented reduction -----------------------
#define NSLICE 16
__global__ __launch_bounds__(256) void k_pool2(const float* __restrict__ h,
                                               const int* __restrict__ start,
                                               float* __restrict__ sums,
                                               unsigned* __restrict__ maxs) {
    int gph = blockIdx.x >> 4;          // / NSLICE
    int sl  = blockIdx.x & (NSLICE - 1);
    int s = start[gph], e1 = start[gph + 1];
    int len = e1 - s;
    int chunk = (len + NSLICE - 1) / NSLICE;
    int r0 = s + sl * chunk;
    int r1 = min(r0 + chunk, e1);
    int j = threadIdx.x & 63, wv = threadIdx.x >> 6;
    float sm = 0.f, mx = 0.f;           // post-ReLU values >= 0
    for (int r = r0 + wv; r < r1; r += 4) {
        float v = h[r * HID + j];
        sm += v;
        mx = fmaxf(mx, v);
    }
    atomicAdd(&sums[gph * HID + j], sm);
    atomicMax(&maxs[gph * HID + j], __float_as_uint(mx));
}

// ---------------- final MLP: relu([mean,max] @ W1 + b1) @ W2 + b2 -----------
__global__ __launch_bounds__(64) void k_mlp(const float* __restrict__ sums,
                                            const unsigned* __restrict__ maxs,
                                            const int* __restrict__ start,
                                            const float* __restrict__ W1,
                                            const float* __restrict__ b1,
                                            const float* __restrict__ W2,
                                            const float* __restrict__ b2,
                                            float* __restrict__ out) {
    int gph = blockIdx.x;
    int j = threadIdx.x;          // 64 threads
    __shared__ float gv[2 * HID];
    int cnt = start[gph + 1] - start[gph];
    float inv = 1.f / fmaxf((float)cnt, 1.f);
    gv[j] = sums[gph * HID + j] * inv;
    float mx = __uint_as_float(maxs[gph * HID + j]);
    gv[HID + j] = (cnt > 0) ? mx : 0.f;
    __syncthreads();
    float acc = b1[j];
#pragma unroll
    for (int k = 0; k < 2 * HID; ++k) acc += gv[k] * W1[k * HID + j];
    acc = fmaxf(acc, 0.f);
    float p = acc * W2[j];
#pragma unroll
    for (int off = 32; off; off >>= 1) p += __shfl_xor(p, off, 64);
    if (j == 0) out[gph] = p + b2[0];
}

extern "C" void kernel_launch(void* const* d_in, const int* in_sizes, int n_in,
                              void* d_out, int out_size, void* d_ws, size_t ws_size,
                              hipStream_t stream) {
    const int*   x     = (const int*)d_in[0];
    const int*   ei    = (const int*)d_in[1];
    const float* ew    = (const float*)d_in[2];
    const int*   batch = (const int*)d_in[3];
    const float* emb   = (const float*)d_in[4];
    const float* convW = (const float*)d_in[5];
    const float* convB = (const float*)d_in[6];
    const float* lnG   = (const float*)d_in[7];
    const float* lnB   = (const float*)d_in[8];
    const float* W1    = (const float*)d_in[9];
    const float* b1    = (const float*)d_in[10];
    const float* W2    = (const float*)d_in[11];
    const float* b2    = (const float*)d_in[12];
    float* out = (float*)d_out;

    // ---- workspace layout (~38.5 MB) ----
    float* hA   = (float*)d_ws;                           // 12.8 MB
    float* m    = hA + (size_t)N_NODES * HID;             // 12.8 MB
    int2*  buf  = (int2*)(m + (size_t)N_NODES * HID);     // 12.81 MB
    int*   gcnt = (int*)(buf + (size_t)N_BUCKETS * BK_CAP); // 1563
    float* sums = (float*)(gcnt + N_BUCKETS);             // 4096
    unsigned* maxs = (unsigned*)(sums + N_GRAPHS * HID);  // 4096
    int*   start = (int*)(maxs + N_GRAPHS * HID);         // 65

    const int* src = ei;
    const int* dst = ei + N_EDGES;

    hipMemsetAsync(gcnt, 0, N_BUCKETS * sizeof(int), stream);
    k_bucket<<<FB_BLOCKS, FB_THREADS, 0, stream>>>(src, dst, ew, gcnt, buf);
    k_misc<<<1, 256, 0, stream>>>(batch, start, sums, maxs);

    for (int L = 0; L < N_LAYERS; ++L) {
        // layer 0 gathers emb rows through x (fused embedding)
        k_linear<<<N_NODES / 4, 256, 0, stream>>>(
            (L == 0) ? emb : hA, (L == 0) ? x : nullptr,
            convW + L * HID * HID, m);
        k_agg<<<N_BUCKETS, 256, 0, stream>>>(
            m, buf, gcnt, convB + L * HID, lnG + L * HID, lnB + L * HID, hA);
    }

    k_pool2<<<N_GRAPHS * NSLICE, 256, 0, stream>>>(hA, start, sums, maxs);
    k_mlp<<<N_GRAPHS, 64, 0, stream>>>(sums, maxs, start, W1, b1, W2, b2, out);
}

// Round 8
// 416.901 us; speedup vs baseline: 4.0028x; 4.0028x over previous
//
#include <hip/hip_runtime.h>

#define N_NODES 50000
#define N_EDGES 1250000
#define HID 64
#define N_LAYERS 3
#define N_GRAPHS 64
#define EPS 1e-5f

// ---- dst-partitioned CSR build ----
#define P_SHIFT 7
#define P_NODES 128                                     // nodes per partition
#define NP ((N_NODES + P_NODES - 1) / P_NODES)          // 391
#define PCAP 4096                                       // slots (mean 3200, +16 sigma)

// ------ m = h @ W ; optional row gather via xidx (fuses embedding layer) ----
__global__ __launch_bounds__(256) void k_linear(const float* __restrict__ h,
                                                const int* __restrict__ xidx,
                                                const float* __restrict__ W,
                                                float* __restrict__ m) {
    __shared__ float Wl[HID * HID];   // 16 KB
    __shared__ float hl[4 * HID];
    int tid = threadIdx.x;
    for (int k = tid; k < HID * HID; k += 256) Wl[k] = W[k];
    int row0 = blockIdx.x * 4;        // 50000 % 4 == 0 -> exact
    {
        int rr = row0 + (tid >> 6);
        int srcrow = xidx ? xidx[rr] : rr;
        hl[tid] = h[srcrow * HID + (tid & 63)];
    }
    __syncthreads();
    int r = tid >> 6, c = tid & 63;
    float acc = 0.f;
#pragma unroll
    for (int k = 0; k < HID; ++k) acc += hl[r * HID + k] * Wl[k * HID + c];
    m[(row0 + r) * HID + c] = acc;
}

// ---- partition edges by dst>>7; per-block contiguous runs (low write-amp) --
__global__ __launch_bounds__(1024) void k_part(const int* __restrict__ src,
                                               const int* __restrict__ dst,
                                               const float* __restrict__ w,
                                               int* __restrict__ pcnt,
                                               int2* __restrict__ part) {
    __shared__ int hist[NP];   // counts, then block base
    __shared__ int cur[NP];
    int t = threadIdx.x;
    for (int k = t; k < NP; k += 1024) { hist[k] = 0; cur[k] = 0; }
    __syncthreads();
    int chunk = (N_EDGES + gridDim.x - 1) / gridDim.x;
    int e0 = blockIdx.x * chunk;
    int e1 = min(e0 + chunk, N_EDGES);
    for (int e = e0 + t; e < e1; e += 1024)
        atomicAdd(&hist[dst[e] >> P_SHIFT], 1);
    __syncthreads();
    for (int k = t; k < NP; k += 1024) {
        int c = hist[k];
        hist[k] = c ? atomicAdd(&pcnt[k], c) : 0;      // reserve block range
    }
    __syncthreads();
    for (int e = e0 + t; e < e1; e += 1024) {
        int d = dst[e];
        int b = d >> P_SHIFT;
        int r = atomicAdd(&cur[b], 1);
        part[(b << 12) + hist[b] + r] =                // PCAP == 4096
            make_int2(((d & (P_NODES - 1)) << 16) | src[e], __float_as_int(w[e]));
    }
}

// ---- per-partition LDS counting sort -> per-node-contiguous CSR (in place) -
__global__ __launch_bounds__(512) void k_sort(int2* __restrict__ part,
                                              const int* __restrict__ pcnt,
                                              int* __restrict__ rowbeg,
                                              int* __restrict__ rowend) {
    __shared__ int2 sbuf[PCAP];        // 32 KB
    __shared__ int cnt[P_NODES], base[P_NODES], cur[P_NODES];
    int p = blockIdx.x, t = threadIdx.x;
    if (t < P_NODES) cnt[t] = 0;
    __syncthreads();
    int n = pcnt[p];
    if (n > PCAP) n = PCAP;
    int2* pb = part + (p << 12);
    for (int i = t; i < n; i += 512) atomicAdd(&cnt[pb[i].x >> 16], 1);
    __syncthreads();
    if (t < P_NODES) base[t] = cnt[t];
    __syncthreads();
    for (int off = 1; off < P_NODES; off <<= 1) {
        int v = (t < P_NODES && t >= off) ? base[t - off] : 0;
        __syncthreads();
        if (t < P_NODES) base[t] += v;                 // inclusive scan
        __syncthreads();
    }
    if (t < P_NODES) cur[t] = base[t] - cnt[t];        // exclusive start
    __syncthreads();
    for (int i = t; i < n; i += 512) {
        int2 e = pb[i];
        int pos = atomicAdd(&cur[e.x >> 16], 1);
        sbuf[pos] = e;
    }
    __syncthreads();
    for (int i = t; i < n; i += 512) pb[i] = sbuf[i];  // streaming write-back
    if (t < P_NODES) {
        int node = p * P_NODES + t;
        if (node < N_NODES) {
            rowbeg[node] = (p << 12) + base[t] - cnt[t];
            rowend[node] = (p << 12) + base[t];
        }
    }
}

// ------- fused: atomic-free gather-aggregate + bias + LayerNorm + ReLU ------
// one wave per node; lane = channel; 16-deep software-pipelined edge loop
__global__ __launch_bounds__(256) void k_agg_ln(const float* __restrict__ m,
                                                const int* __restrict__ rowbeg,
                                                const int* __restrict__ rowend,
                                                const int2* __restrict__ csr,
                                                const float* __restrict__ bias,
                                                const float* __restrict__ g,
                                                const float* __restrict__ b,
                                                float* __restrict__ hout) {
    int t = blockIdx.x * 256 + threadIdx.x;
    int row = t >> 6, j = t & 63;
    if (row >= N_NODES) return;
    int p0 = rowbeg[row], p1 = rowend[row];
    float a[16];
#pragma unroll
    for (int q = 0; q < 16; ++q) a[q] = 0.f;
    for (int p = p0; p < p1; p += 16) {
        int last = p1 - 1;
        int2 e[16];
        float wv[16];
#pragma unroll
        for (int q = 0; q < 16; ++q) e[q] = csr[min(p + q, last)];
#pragma unroll
        for (int q = 0; q < 16; ++q)
            wv[q] = (p + q < p1) ? __int_as_float(e[q].y) : 0.f;
#pragma unroll
        for (int q = 0; q < 16; ++q)
            a[q] += m[(e[q].x & 0xFFFF) * HID + j] * wv[q];
    }
    float acc = (((a[0] + a[1]) + (a[2] + a[3])) + ((a[4] + a[5]) + (a[6] + a[7])))
              + (((a[8] + a[9]) + (a[10] + a[11])) + ((a[12] + a[13]) + (a[14] + a[15])));
    float v = acc + bias[j];
    float s = v;
#pragma unroll
    for (int off = 32; off; off >>= 1) s += __shfl_xor(s, off, 64);
    float mu = s * (1.f / 64.f);
    float d = v - mu;
    float vv = d * d;
#pragma unroll
    for (int off = 32; off; off >>= 1) vv += __shfl_xor(vv, off, 64);
    float var = vv * (1.f / 64.f);
    float y = d * rsqrtf(var + EPS) * g[j] + b[j];
    hout[row * HID + j] = fmaxf(y, 0.f);
}

// ---- misc: graph bounds (batch sorted) + zero pooling scratch --------------
__global__ __launch_bounds__(256) void k_misc(const int* __restrict__ batch,
                                              int* __restrict__ start,
                                              float* __restrict__ sums,
                                              unsigned* __restrict__ maxs) {
    int t = threadIdx.x;
    if (t <= N_GRAPHS) {
        int lo = 0, hi = N_NODES;
        while (lo < hi) {
            int mid = (lo + hi) >> 1;
            if (batch[mid] < t) lo = mid + 1; else hi = mid;
        }
        start[t] = lo;
    }
    for (int k = t; k < N_GRAPHS * HID; k += 256) {
        sums[k] = 0.f;
        maxs[k] = 0u;
    }
}

// ---------------- pooling: sliced segmented reduction -----------------------
#define NSLICE 16
__global__ __launch_bounds__(256) void k_pool2(const float* __restrict__ h,
                                               const int* __restrict__ start,
                                               float* __restrict__ sums,
                                               unsigned* __restrict__ maxs) {
    int gph = blockIdx.x >> 4;          // / NSLICE
    int sl  = blockIdx.x & (NSLICE - 1);
    int s = start[gph], e1 = start[gph + 1];
    int len = e1 - s;
    int chunk = (len + NSLICE - 1) / NSLICE;
    int r0 = s + sl * chunk;
    int r1 = min(r0 + chunk, e1);
    int j = threadIdx.x & 63, wv = threadIdx.x >> 6;
    float sm = 0.f, mx = 0.f;           // post-ReLU values >= 0
    for (int r = r0 + wv; r < r1; r += 4) {
        float v = h[r * HID + j];
        sm += v;
        mx = fmaxf(mx, v);
    }
    atomicAdd(&sums[gph * HID + j], sm);
    atomicMax(&maxs[gph * HID + j], __float_as_uint(mx));
}

// ---------------- final MLP: relu([mean,max] @ W1 + b1) @ W2 + b2 -----------
__global__ __launch_bounds__(64) void k_mlp(const float* __restrict__ sums,
                                            const unsigned* __restrict__ maxs,
                                            const int* __restrict__ start,
                                            const float* __restrict__ W1,
                                            const float* __restrict__ b1,
                                            const float* __restrict__ W2,
                                            const float* __restrict__ b2,
                                            float* __restrict__ out) {
    int gph = blockIdx.x;
    int j = threadIdx.x;          // 64 threads
    __shared__ float gv[2 * HID];
    int cnt = start[gph + 1] - start[gph];
    float inv = 1.f / fmaxf((float)cnt, 1.f);
    gv[j] = sums[gph * HID + j] * inv;
    float mx = __uint_as_float(maxs[gph * HID + j]);
    gv[HID + j] = (cnt > 0) ? mx : 0.f;
    __syncthreads();
    float acc = b1[j];
#pragma unroll
    for (int k = 0; k < 2 * HID; ++k) acc += gv[k] * W1[k * HID + j];
    acc = fmaxf(acc, 0.f);
    float p = acc * W2[j];
#pragma unroll
    for (int off = 32; off; off >>= 1) p += __shfl_xor(p, off, 64);
    if (j == 0) out[gph] = p + b2[0];
}

extern "C" void kernel_launch(void* const* d_in, const int* in_sizes, int n_in,
                              void* d_out, int out_size, void* d_ws, size_t ws_size,
                              hipStream_t stream) {
    const int*   x     = (const int*)d_in[0];
    const int*   ei    = (const int*)d_in[1];
    const float* ew    = (const float*)d_in[2];
    const int*   batch = (const int*)d_in[3];
    const float* emb   = (const float*)d_in[4];
    const float* convW = (const float*)d_in[5];
    const float* convB = (const float*)d_in[6];
    const float* lnG   = (const float*)d_in[7];
    const float* lnB   = (const float*)d_in[8];
    const float* W1    = (const float*)d_in[9];
    const float* b1    = (const float*)d_in[10];
    const float* W2    = (const float*)d_in[11];
    const float* b2    = (const float*)d_in[12];
    float* out = (float*)d_out;

    // ---- workspace layout (~39 MB) ----
    float* hA     = (float*)d_ws;                         // 12.8 MB
    float* m      = hA + (size_t)N_NODES * HID;           // 12.8 MB
    int2*  part   = (int2*)(m + (size_t)N_NODES * HID);   // 12.81 MB (also CSR)
    int*   pcnt   = (int*)(part + (size_t)NP * PCAP);     // 391
    int*   rowbeg = pcnt + NP;                            // 50000
    int*   rowend = rowbeg + N_NODES;                     // 50000
    float* sums   = (float*)(rowend + N_NODES);           // 4096
    unsigned* maxs = (unsigned*)(sums + N_GRAPHS * HID);  // 4096
    int*   start  = (int*)(maxs + N_GRAPHS * HID);        // 65

    const int* src = ei;
    const int* dst = ei + N_EDGES;

    hipMemsetAsync(pcnt, 0, NP * sizeof(int), stream);
    k_part<<<256, 1024, 0, stream>>>(src, dst, ew, pcnt, part);
    k_sort<<<NP, 512, 0, stream>>>(part, pcnt, rowbeg, rowend);
    k_misc<<<1, 256, 0, stream>>>(batch, start, sums, maxs);

    for (int L = 0; L < N_LAYERS; ++L) {
        // layer 0 gathers emb rows through x (fused embedding)
        k_linear<<<N_NODES / 4, 256, 0, stream>>>(
            (L == 0) ? emb : hA, (L == 0) ? x : nullptr,
            convW + L * HID * HID, m);
        k_agg_ln<<<(N_NODES * 64) / 256, 256, 0, stream>>>(
            m, rowbeg, rowend, part, convB + L * HID,
            lnG + L * HID, lnB + L * HID, hA);
    }

    k_pool2<<<N_GRAPHS * NSLICE, 256, 0, stream>>>(hA, start, sums, maxs);
    k_mlp<<<N_GRAPHS, 64, 0, stream>>>(sums, maxs, start, W1, b1, W2, b2, out);
}

// Round 9
// 323.718 us; speedup vs baseline: 5.1550x; 1.2879x over previous
//
#include <hip/hip_runtime.h>

#define N_NODES 50000
#define N_EDGES 1250000
#define HID 64
#define N_LAYERS 3
#define N_GRAPHS 64
#define EPS 1e-5f

// ---- dst-partitioned CSR build ----
#define P_SHIFT 7
#define P_NODES 128                                     // nodes per partition
#define NP ((N_NODES + P_NODES - 1) / P_NODES)          // 391
#define PCAP 4096                                       // slots (mean 3200, +16 sigma)

#define LIN_ROWS 16                                     // rows per k_linear block

// ------ m = h @ W ; optional row gather via xidx (fuses embedding layer) ----
// 1024 thr = 16 waves; wave = one row; h row scalarized (s_load), W in LDS
__global__ __launch_bounds__(1024) void k_linear(const float* __restrict__ h,
                                                 const int* __restrict__ xidx,
                                                 const float* __restrict__ W,
                                                 float* __restrict__ m) {
    __shared__ float Wl[HID * HID];   // 16 KB
    int tid = threadIdx.x;
    for (int k = tid; k < HID * HID; k += 1024) Wl[k] = W[k];
    __syncthreads();
    int c = tid & 63;
    int wv = tid >> 6;                // 0..15
    int row = blockIdx.x * LIN_ROWS + wv;   // 50000 % 16 == 0 -> exact
    int srcrow = xidx ? xidx[row] : row;
    srcrow = __builtin_amdgcn_readfirstlane(srcrow);
    const float* __restrict__ hr = h + (size_t)srcrow * HID;
    float acc = 0.f;
#pragma unroll
    for (int k = 0; k < HID; ++k) acc += hr[k] * Wl[k * HID + c];
    m[row * HID + c] = acc;
}

// ---- partition edges by dst>>7; per-block contiguous runs (low write-amp) --
__global__ __launch_bounds__(1024) void k_part(const int* __restrict__ src,
                                               const int* __restrict__ dst,
                                               const float* __restrict__ w,
                                               int* __restrict__ pcnt,
                                               int2* __restrict__ part) {
    __shared__ int hist[NP];   // counts, then block base
    __shared__ int cur[NP];
    int t = threadIdx.x;
    for (int k = t; k < NP; k += 1024) { hist[k] = 0; cur[k] = 0; }
    __syncthreads();
    int chunk = (N_EDGES + gridDim.x - 1) / gridDim.x;
    int e0 = blockIdx.x * chunk;
    int e1 = min(e0 + chunk, N_EDGES);
    for (int e = e0 + t; e < e1; e += 1024)
        atomicAdd(&hist[dst[e] >> P_SHIFT], 1);
    __syncthreads();
    for (int k = t; k < NP; k += 1024) {
        int c = hist[k];
        hist[k] = c ? atomicAdd(&pcnt[k], c) : 0;      // reserve block range
    }
    __syncthreads();
    for (int e = e0 + t; e < e1; e += 1024) {
        int d = dst[e];
        int b = d >> P_SHIFT;
        int r = atomicAdd(&cur[b], 1);
        part[(b << 12) + hist[b] + r] =                // PCAP == 4096
            make_int2(((d & (P_NODES - 1)) << 16) | src[e], __float_as_int(w[e]));
    }
}

// ---- per-partition LDS counting sort -> per-node-contiguous CSR (in place) -
// block 0 also computes graph bounds + zeroes pooling scratch (fused k_misc)
__global__ __launch_bounds__(512) void k_sort(int2* __restrict__ part,
                                              const int* __restrict__ pcnt,
                                              int* __restrict__ rowbeg,
                                              int* __restrict__ rowend,
                                              const int* __restrict__ batch,
                                              int* __restrict__ start,
                                              float* __restrict__ sums,
                                              unsigned* __restrict__ maxs) {
    __shared__ int2 sbuf[PCAP];        // 32 KB
    __shared__ int cnt[P_NODES], base[P_NODES], cur[P_NODES];
    int p = blockIdx.x, t = threadIdx.x;
    if (t < P_NODES) cnt[t] = 0;
    __syncthreads();
    int n = pcnt[p];
    if (n > PCAP) n = PCAP;
    int2* pb = part + (p << 12);
    for (int i = t; i < n; i += 512) atomicAdd(&cnt[pb[i].x >> 16], 1);
    __syncthreads();
    if (t < P_NODES) base[t] = cnt[t];
    __syncthreads();
    for (int off = 1; off < P_NODES; off <<= 1) {
        int v = (t < P_NODES && t >= off) ? base[t - off] : 0;
        __syncthreads();
        if (t < P_NODES) base[t] += v;                 // inclusive scan
        __syncthreads();
    }
    if (t < P_NODES) cur[t] = base[t] - cnt[t];        // exclusive start
    __syncthreads();
    for (int i = t; i < n; i += 512) {
        int2 e = pb[i];
        int pos = atomicAdd(&cur[e.x >> 16], 1);
        sbuf[pos] = e;
    }
    __syncthreads();
    for (int i = t; i < n; i += 512) pb[i] = sbuf[i];  // streaming write-back
    if (t < P_NODES) {
        int node = p * P_NODES + t;
        if (node < N_NODES) {
            rowbeg[node] = (p << 12) + base[t] - cnt[t];
            rowend[node] = (p << 12) + base[t];
        }
    }
    if (p == 0) {                                      // fused misc work
        if (t <= N_GRAPHS) {
            int lo = 0, hi = N_NODES;
            while (lo < hi) {
                int mid = (lo + hi) >> 1;
                if (batch[mid] < t) lo = mid + 1; else hi = mid;
            }
            start[t] = lo;
        }
        for (int k = t; k < N_GRAPHS * HID; k += 512) {
            sums[k] = 0.f;
            maxs[k] = 0u;
        }
    }
}

// ------- fused: atomic-free gather-aggregate + bias + LayerNorm + ReLU ------
// one wave per node; lane = channel; SCALARIZED edge stream:
// csr entries / bounds / m-row bases live in SGPRs (readfirstlane), so the
// vector side is just global_load_dword(saddr+lane*4) + v_fmac per edge.
__global__ __launch_bounds__(256) void k_agg_ln(const float* __restrict__ m,
                                                const int* __restrict__ rowbeg,
                                                const int* __restrict__ rowend,
                                                const int2* __restrict__ csr,
                                                const float* __restrict__ bias,
                                                const float* __restrict__ g,
                                                const float* __restrict__ b,
                                                float* __restrict__ hout) {
    int t = blockIdx.x * 256 + threadIdx.x;
    int row = t >> 6, j = t & 63;
    if (row >= N_NODES) return;
    int p0 = __builtin_amdgcn_readfirstlane(rowbeg[row]);
    int p1 = __builtin_amdgcn_readfirstlane(rowend[row]);
    int n = p1 - p0;
    int pf = p0 + (n & ~7);
    float a0 = 0.f, a1 = 0.f, a2 = 0.f, a3 = 0.f;
    float a4 = 0.f, a5 = 0.f, a6 = 0.f, a7 = 0.f;
    for (int p = p0; p < pf; p += 8) {
        int s0, s1, s2, s3, s4, s5, s6, s7;
        float w0, w1, w2, w3, w4, w5, w6, w7;
        {
            int2 e;
            e = csr[p + 0]; s0 = __builtin_amdgcn_readfirstlane(e.x) & 0xFFFF;
            w0 = __int_as_float(__builtin_amdgcn_readfirstlane(e.y));
            e = csr[p + 1]; s1 = __builtin_amdgcn_readfirstlane(e.x) & 0xFFFF;
            w1 = __int_as_float(__builtin_amdgcn_readfirstlane(e.y));
            e = csr[p + 2]; s2 = __builtin_amdgcn_readfirstlane(e.x) & 0xFFFF;
            w2 = __int_as_float(__builtin_amdgcn_readfirstlane(e.y));
            e = csr[p + 3]; s3 = __builtin_amdgcn_readfirstlane(e.x) & 0xFFFF;
            w3 = __int_as_float(__builtin_amdgcn_readfirstlane(e.y));
            e = csr[p + 4]; s4 = __builtin_amdgcn_readfirstlane(e.x) & 0xFFFF;
            w4 = __int_as_float(__builtin_amdgcn_readfirstlane(e.y));
            e = csr[p + 5]; s5 = __builtin_amdgcn_readfirstlane(e.x) & 0xFFFF;
            w5 = __int_as_float(__builtin_amdgcn_readfirstlane(e.y));
            e = csr[p + 6]; s6 = __builtin_amdgcn_readfirstlane(e.x) & 0xFFFF;
            w6 = __int_as_float(__builtin_amdgcn_readfirstlane(e.y));
            e = csr[p + 7]; s7 = __builtin_amdgcn_readfirstlane(e.x) & 0xFFFF;
            w7 = __int_as_float(__builtin_amdgcn_readfirstlane(e.y));
        }
        // 8 independent gathers in flight, scalar base + lane offset
        a0 += m[s0 * HID + j] * w0;
        a1 += m[s1 * HID + j] * w1;
        a2 += m[s2 * HID + j] * w2;
        a3 += m[s3 * HID + j] * w3;
        a4 += m[s4 * HID + j] * w4;
        a5 += m[s5 * HID + j] * w5;
        a6 += m[s6 * HID + j] * w6;
        a7 += m[s7 * HID + j] * w7;
    }
    float acc = ((a0 + a1) + (a2 + a3)) + ((a4 + a5) + (a6 + a7));
    for (int p = pf; p < p1; ++p) {                    // tail <= 7, no clamps
        int2 e = csr[p];
        int sx = __builtin_amdgcn_readfirstlane(e.x) & 0xFFFF;
        float we = __int_as_float(__builtin_amdgcn_readfirstlane(e.y));
        acc += m[sx * HID + j] * we;
    }
    float v = acc + bias[j];
    float s = v;
#pragma unroll
    for (int off = 32; off; off >>= 1) s += __shfl_xor(s, off, 64);
    float mu = s * (1.f / 64.f);
    float d = v - mu;
    float vv = d * d;
#pragma unroll
    for (int off = 32; off; off >>= 1) vv += __shfl_xor(vv, off, 64);
    float var = vv * (1.f / 64.f);
    float y = d * rsqrtf(var + EPS) * g[j] + b[j];
    hout[row * HID + j] = fmaxf(y, 0.f);
}

// ---------------- pooling: sliced segmented reduction -----------------------
#define NSLICE 16
__global__ __launch_bounds__(256) void k_pool2(const float* __restrict__ h,
                                               const int* __restrict__ start,
                                               float* __restrict__ sums,
                                               unsigned* __restrict__ maxs) {
    int gph = blockIdx.x >> 4;          // / NSLICE
    int sl  = blockIdx.x & (NSLICE - 1);
    int s = start[gph], e1 = start[gph + 1];
    int len = e1 - s;
    int chunk = (len + NSLICE - 1) / NSLICE;
    int r0 = s + sl * chunk;
    int r1 = min(r0 + chunk, e1);
    int j = threadIdx.x & 63, wv = threadIdx.x >> 6;
    float sm = 0.f, mx = 0.f;           // post-ReLU values >= 0
    for (int r = r0 + wv; r < r1; r += 4) {
        float v = h[r * HID + j];
        sm += v;
        mx = fmaxf(mx, v);
    }
    atomicAdd(&sums[gph * HID + j], sm);
    atomicMax(&maxs[gph * HID + j], __float_as_uint(mx));
}

// ---------------- final MLP: relu([mean,max] @ W1 + b1) @ W2 + b2 -----------
__global__ __launch_bounds__(64) void k_mlp(const float* __restrict__ sums,
                                            const unsigned* __restrict__ maxs,
                                            const int* __restrict__ start,
                                            const float* __restrict__ W1,
                                            const float* __restrict__ b1,
                                            const float* __restrict__ W2,
                                            const float* __restrict__ b2,
                                            float* __restrict__ out) {
    int gph = blockIdx.x;
    int j = threadIdx.x;          // 64 threads
    __shared__ float gv[2 * HID];
    int cnt = start[gph + 1] - start[gph];
    float inv = 1.f / fmaxf((float)cnt, 1.f);
    gv[j] = sums[gph * HID + j] * inv;
    float mx = __uint_as_float(maxs[gph * HID + j]);
    gv[HID + j] = (cnt > 0) ? mx : 0.f;
    __syncthreads();
    float acc = b1[j];
#pragma unroll
    for (int k = 0; k < 2 * HID; ++k) acc += gv[k] * W1[k * HID + j];
    acc = fmaxf(acc, 0.f);
    float p = acc * W2[j];
#pragma unroll
    for (int off = 32; off; off >>= 1) p += __shfl_xor(p, off, 64);
    if (j == 0) out[gph] = p + b2[0];
}

extern "C" void kernel_launch(void* const* d_in, const int* in_sizes, int n_in,
                              void* d_out, int out_size, void* d_ws, size_t ws_size,
                              hipStream_t stream) {
    const int*   x     = (const int*)d_in[0];
    const int*   ei    = (const int*)d_in[1];
    const float* ew    = (const float*)d_in[2];
    const int*   batch = (const int*)d_in[3];
    const float* emb   = (const float*)d_in[4];
    const float* convW = (const float*)d_in[5];
    const float* convB = (const float*)d_in[6];
    const float* lnG   = (const float*)d_in[7];
    const float* lnB   = (const float*)d_in[8];
    const float* W1    = (const float*)d_in[9];
    const float* b1    = (const float*)d_in[10];
    const float* W2    = (const float*)d_in[11];
    const float* b2    = (const float*)d_in[12];
    float* out = (float*)d_out;

    // ---- workspace layout (~39 MB) ----
    float* hA     = (float*)d_ws;                         // 12.8 MB
    float* m      = hA + (size_t)N_NODES * HID;           // 12.8 MB
    int2*  part   = (int2*)(m + (size_t)N_NODES * HID);   // 12.81 MB (also CSR)
    int*   pcnt   = (int*)(part + (size_t)NP * PCAP);     // 391
    int*   rowbeg = pcnt + NP;                            // 50000
    int*   rowend = rowbeg + N_NODES;                     // 50000
    float* sums   = (float*)(rowend + N_NODES);           // 4096
    unsigned* maxs = (unsigned*)(sums + N_GRAPHS * HID);  // 4096
    int*   start  = (int*)(maxs + N_GRAPHS * HID);        // 65

    const int* src = ei;
    const int* dst = ei + N_EDGES;

    hipMemsetAsync(pcnt, 0, NP * sizeof(int), stream);
    k_part<<<256, 1024, 0, stream>>>(src, dst, ew, pcnt, part);
    k_sort<<<NP, 512, 0, stream>>>(part, pcnt, rowbeg, rowend,
                                   batch, start, sums, maxs);

    for (int L = 0; L < N_LAYERS; ++L) {
        // layer 0 gathers emb rows through x (fused embedding)
        k_linear<<<N_NODES / LIN_ROWS, 1024, 0, stream>>>(
            (L == 0) ? emb : hA, (L == 0) ? x : nullptr,
            convW + L * HID * HID, m);
        k_agg_ln<<<(N_NODES * 64) / 256, 256, 0, stream>>>(
            m, rowbeg, rowend, part, convB + L * HID,
            lnG + L * HID, lnB + L * HID, hA);
    }

    k_pool2<<<N_GRAPHS * NSLICE, 256, 0, stream>>>(hA, start, sums, maxs);
    k_mlp<<<N_GRAPHS, 64, 0, stream>>>(sums, maxs, start, W1, b1, W2, b2, out);
}

// Round 10
// 305.636 us; speedup vs baseline: 5.4600x; 1.0592x over previous
//
#include <hip/hip_runtime.h>

#define N_NODES 50000
#define N_EDGES 1250000
#define HID 64
#define N_LAYERS 3
#define N_GRAPHS 64
#define EPS 1e-5f

// ---- dst-partitioned CSR build ----
#define P_SHIFT 7
#define P_NODES 128                                     // nodes per partition
#define NP ((N_NODES + P_NODES - 1) / P_NODES)          // 391
#define PCAP 4096                                       // slots (mean 3200, +16 sigma)

#define LB_NODES 8                                      // nodes per k_layer block

// ---------------- embed gather: h0[i][:] = emb[x[i]][:] (float4) ------------
__global__ __launch_bounds__(256) void k_embed(const int* __restrict__ x,
                                               const float4* __restrict__ emb4,
                                               float4* __restrict__ h4) {
    int i = blockIdx.x * 256 + threadIdx.x;           // over N_NODES * 16
    if (i < N_NODES * 16) {
        int row = i >> 4, q = i & 15;
        h4[i] = emb4[x[row] * 16 + q];
    }
}

// ---- partition edges by dst>>7; per-block contiguous runs (low write-amp) --
__global__ __launch_bounds__(1024) void k_part(const int* __restrict__ src,
                                               const int* __restrict__ dst,
                                               const float* __restrict__ w,
                                               int* __restrict__ pcnt,
                                               int2* __restrict__ part) {
    __shared__ int hist[NP];   // counts, then block base
    __shared__ int cur[NP];
    int t = threadIdx.x;
    for (int k = t; k < NP; k += 1024) { hist[k] = 0; cur[k] = 0; }
    __syncthreads();
    int chunk = (N_EDGES + gridDim.x - 1) / gridDim.x;
    int e0 = blockIdx.x * chunk;
    int e1 = min(e0 + chunk, N_EDGES);
    for (int e = e0 + t; e < e1; e += 1024)
        atomicAdd(&hist[dst[e] >> P_SHIFT], 1);
    __syncthreads();
    for (int k = t; k < NP; k += 1024) {
        int c = hist[k];
        hist[k] = c ? atomicAdd(&pcnt[k], c) : 0;      // reserve block range
    }
    __syncthreads();
    for (int e = e0 + t; e < e1; e += 1024) {
        int d = dst[e];
        int b = d >> P_SHIFT;
        int r = atomicAdd(&cur[b], 1);
        part[(b << 12) + hist[b] + r] =                // PCAP == 4096
            make_int2(((d & (P_NODES - 1)) << 16) | src[e], __float_as_int(w[e]));
    }
}

// ---- per-partition LDS counting sort -> per-node-contiguous CSR (in place) -
// block 0 also computes graph bounds + zeroes pooling scratch
__global__ __launch_bounds__(512) void k_sort(int2* __restrict__ part,
                                              const int* __restrict__ pcnt,
                                              int* __restrict__ rowbeg,
                                              int* __restrict__ rowend,
                                              const int* __restrict__ batch,
                                              int* __restrict__ start,
                                              float* __restrict__ sums,
                                              unsigned* __restrict__ maxs) {
    __shared__ int2 sbuf[PCAP];        // 32 KB
    __shared__ int cnt[P_NODES], base[P_NODES], cur[P_NODES];
    int p = blockIdx.x, t = threadIdx.x;
    if (t < P_NODES) cnt[t] = 0;
    __syncthreads();
    int n = pcnt[p];
    if (n > PCAP) n = PCAP;
    int2* pb = part + (p << 12);
    for (int i = t; i < n; i += 512) atomicAdd(&cnt[pb[i].x >> 16], 1);
    __syncthreads();
    if (t < P_NODES) base[t] = cnt[t];
    __syncthreads();
    for (int off = 1; off < P_NODES; off <<= 1) {
        int v = (t < P_NODES && t >= off) ? base[t - off] : 0;
        __syncthreads();
        if (t < P_NODES) base[t] += v;                 // inclusive scan
        __syncthreads();
    }
    if (t < P_NODES) cur[t] = base[t] - cnt[t];        // exclusive start
    __syncthreads();
    for (int i = t; i < n; i += 512) {
        int2 e = pb[i];
        int pos = atomicAdd(&cur[e.x >> 16], 1);
        sbuf[pos] = e;
    }
    __syncthreads();
    for (int i = t; i < n; i += 512) pb[i] = sbuf[i];  // streaming write-back
    if (t < P_NODES) {
        int node = p * P_NODES + t;
        if (node < N_NODES) {
            rowbeg[node] = (p << 12) + base[t] - cnt[t];
            rowend[node] = (p << 12) + base[t];
        }
    }
    if (p == 0) {                                      // fused misc work
        if (t <= N_GRAPHS) {
            int lo = 0, hi = N_NODES;
            while (lo < hi) {
                int mid = (lo + hi) >> 1;
                if (batch[mid] < t) lo = mid + 1; else hi = mid;
            }
            start[t] = lo;
        }
        for (int k = t; k < N_GRAPHS * HID; k += 512) {
            sums[k] = 0.f;
            maxs[k] = 0u;
        }
    }
}

// ---- fused layer: gather-aggregate h[src]*w  ->  @W  -> bias+LN+ReLU ------
// (segment_sum is linear: agg before the dense transform)
// 512 thr = 8 waves; wave = one node; lane = channel.
// Edge stream scalarized (SGPR); matvec uses LDS-staged W + agg broadcast.
__global__ __launch_bounds__(512) void k_layer(const float* __restrict__ h,
                                               const int* __restrict__ rowbeg,
                                               const int* __restrict__ rowend,
                                               const int2* __restrict__ csr,
                                               const float* __restrict__ W,
                                               const float* __restrict__ bias,
                                               const float* __restrict__ g,
                                               const float* __restrict__ b,
                                               float* __restrict__ hout) {
    __shared__ float Wl[HID * HID];           // 16 KB
    __shared__ float aggl[LB_NODES][HID];     // 2 KB
    int tid = threadIdx.x;
    for (int k = tid; k < HID * HID; k += 512) Wl[k] = W[k];
    __syncthreads();
    int wv = tid >> 6, j = tid & 63;
    int row = blockIdx.x * LB_NODES + wv;     // 50000 % 8 == 0 -> exact
    int p0 = __builtin_amdgcn_readfirstlane(rowbeg[row]);
    int p1 = __builtin_amdgcn_readfirstlane(rowend[row]);
    int n = p1 - p0;
    int pf = p0 + (n & ~7);
    float a0 = 0.f, a1 = 0.f, a2 = 0.f, a3 = 0.f;
    float a4 = 0.f, a5 = 0.f, a6 = 0.f, a7 = 0.f;
    for (int p = p0; p < pf; p += 8) {
        int s0, s1, s2, s3, s4, s5, s6, s7;
        float w0, w1, w2, w3, w4, w5, w6, w7;
        {
            int2 e;
            e = csr[p + 0]; s0 = __builtin_amdgcn_readfirstlane(e.x) & 0xFFFF;
            w0 = __int_as_float(__builtin_amdgcn_readfirstlane(e.y));
            e = csr[p + 1]; s1 = __builtin_amdgcn_readfirstlane(e.x) & 0xFFFF;
            w1 = __int_as_float(__builtin_amdgcn_readfirstlane(e.y));
            e = csr[p + 2]; s2 = __builtin_amdgcn_readfirstlane(e.x) & 0xFFFF;
            w2 = __int_as_float(__builtin_amdgcn_readfirstlane(e.y));
            e = csr[p + 3]; s3 = __builtin_amdgcn_readfirstlane(e.x) & 0xFFFF;
            w3 = __int_as_float(__builtin_amdgcn_readfirstlane(e.y));
            e = csr[p + 4]; s4 = __builtin_amdgcn_readfirstlane(e.x) & 0xFFFF;
            w4 = __int_as_float(__builtin_amdgcn_readfirstlane(e.y));
            e = csr[p + 5]; s5 = __builtin_amdgcn_readfirstlane(e.x) & 0xFFFF;
            w5 = __int_as_float(__builtin_amdgcn_readfirstlane(e.y));
            e = csr[p + 6]; s6 = __builtin_amdgcn_readfirstlane(e.x) & 0xFFFF;
            w6 = __int_as_float(__builtin_amdgcn_readfirstlane(e.y));
            e = csr[p + 7]; s7 = __builtin_amdgcn_readfirstlane(e.x) & 0xFFFF;
            w7 = __int_as_float(__builtin_amdgcn_readfirstlane(e.y));
        }
        a0 += h[s0 * HID + j] * w0;
        a1 += h[s1 * HID + j] * w1;
        a2 += h[s2 * HID + j] * w2;
        a3 += h[s3 * HID + j] * w3;
        a4 += h[s4 * HID + j] * w4;
        a5 += h[s5 * HID + j] * w5;
        a6 += h[s6 * HID + j] * w6;
        a7 += h[s7 * HID + j] * w7;
    }
    float acc = ((a0 + a1) + (a2 + a3)) + ((a4 + a5) + (a6 + a7));
    for (int p = pf; p < p1; ++p) {                    // tail <= 7, no clamps
        int2 e = csr[p];
        int sx = __builtin_amdgcn_readfirstlane(e.x) & 0xFFFF;
        float we = __int_as_float(__builtin_amdgcn_readfirstlane(e.y));
        acc += h[sx * HID + j] * we;
    }
    // dense transform on the aggregated row (per-wave matvec)
    aggl[wv][j] = acc;
    float mv = 0.f;
#pragma unroll 16
    for (int k = 0; k < HID; ++k) mv += aggl[wv][k] * Wl[k * HID + j];
    float v = mv + bias[j];
    float s = v;
#pragma unroll
    for (int off = 32; off; off >>= 1) s += __shfl_xor(s, off, 64);
    float mu = s * (1.f / 64.f);
    float d = v - mu;
    float vv = d * d;
#pragma unroll
    for (int off = 32; off; off >>= 1) vv += __shfl_xor(vv, off, 64);
    float var = vv * (1.f / 64.f);
    float y = d * rsqrtf(var + EPS) * g[j] + b[j];
    hout[row * HID + j] = fmaxf(y, 0.f);
}

// ---------------- pooling: sliced segmented reduction -----------------------
#define NSLICE 16
__global__ __launch_bounds__(256) void k_pool2(const float* __restrict__ h,
                                               const int* __restrict__ start,
                                               float* __restrict__ sums,
                                               unsigned* __restrict__ maxs) {
    int gph = blockIdx.x >> 4;          // / NSLICE
    int sl  = blockIdx.x & (NSLICE - 1);
    int s = start[gph], e1 = start[gph + 1];
    int len = e1 - s;
    int chunk = (len + NSLICE - 1) / NSLICE;
    int r0 = s + sl * chunk;
    int r1 = min(r0 + chunk, e1);
    int j = threadIdx.x & 63, wv = threadIdx.x >> 6;
    float sm = 0.f, mx = 0.f;           // post-ReLU values >= 0
    for (int r = r0 + wv; r < r1; r += 4) {
        float v = h[r * HID + j];
        sm += v;
        mx = fmaxf(mx, v);
    }
    atomicAdd(&sums[gph * HID + j], sm);
    atomicMax(&maxs[gph * HID + j], __float_as_uint(mx));
}

// ---------------- final MLP: relu([mean,max] @ W1 + b1) @ W2 + b2 -----------
__global__ __launch_bounds__(64) void k_mlp(const float* __restrict__ sums,
                                            const unsigned* __restrict__ maxs,
                                            const int* __restrict__ start,
                                            const float* __restrict__ W1,
                                            const float* __restrict__ b1,
                                            const float* __restrict__ W2,
                                            const float* __restrict__ b2,
                                            float* __restrict__ out) {
    int gph = blockIdx.x;
    int j = threadIdx.x;          // 64 threads
    __shared__ float gv[2 * HID];
    int cnt = start[gph + 1] - start[gph];
    float inv = 1.f / fmaxf((float)cnt, 1.f);
    gv[j] = sums[gph * HID + j] * inv;
    float mx = __uint_as_float(maxs[gph * HID + j]);
    gv[HID + j] = (cnt > 0) ? mx : 0.f;
    __syncthreads();
    float acc = b1[j];
#pragma unroll
    for (int k = 0; k < 2 * HID; ++k) acc += gv[k] * W1[k * HID + j];
    acc = fmaxf(acc, 0.f);
    float p = acc * W2[j];
#pragma unroll
    for (int off = 32; off; off >>= 1) p += __shfl_xor(p, off, 64);
    if (j == 0) out[gph] = p + b2[0];
}

extern "C" void kernel_launch(void* const* d_in, const int* in_sizes, int n_in,
                              void* d_out, int out_size, void* d_ws, size_t ws_size,
                              hipStream_t stream) {
    const int*   x     = (const int*)d_in[0];
    const int*   ei    = (const int*)d_in[1];
    const float* ew    = (const float*)d_in[2];
    const int*   batch = (const int*)d_in[3];
    const float* emb   = (const float*)d_in[4];
    const float* convW = (const float*)d_in[5];
    const float* convB = (const float*)d_in[6];
    const float* lnG   = (const float*)d_in[7];
    const float* lnB   = (const float*)d_in[8];
    const float* W1    = (const float*)d_in[9];
    const float* b1    = (const float*)d_in[10];
    const float* W2    = (const float*)d_in[11];
    const float* b2    = (const float*)d_in[12];
    float* out = (float*)d_out;

    // ---- workspace layout (~39 MB) ----
    float* hA     = (float*)d_ws;                         // 12.8 MB
    float* hB     = hA + (size_t)N_NODES * HID;           // 12.8 MB
    int2*  part   = (int2*)(hB + (size_t)N_NODES * HID);  // 12.81 MB (CSR)
    int*   pcnt   = (int*)(part + (size_t)NP * PCAP);     // 391
    int*   rowbeg = pcnt + NP;                            // 50000
    int*   rowend = rowbeg + N_NODES;                     // 50000
    float* sums   = (float*)(rowend + N_NODES);           // 4096
    unsigned* maxs = (unsigned*)(sums + N_GRAPHS * HID);  // 4096
    int*   start  = (int*)(maxs + N_GRAPHS * HID);        // 65

    const int* src = ei;
    const int* dst = ei + N_EDGES;

    hipMemsetAsync(pcnt, 0, NP * sizeof(int), stream);
    k_part<<<256, 1024, 0, stream>>>(src, dst, ew, pcnt, part);
    k_sort<<<NP, 512, 0, stream>>>(part, pcnt, rowbeg, rowend,
                                   batch, start, sums, maxs);
    k_embed<<<(N_NODES * 16 + 255) / 256, 256, 0, stream>>>(
        x, (const float4*)emb, (float4*)hA);

    float* bufs[2] = { hA, hB };
    for (int L = 0; L < N_LAYERS; ++L) {
        k_layer<<<N_NODES / LB_NODES, 512, 0, stream>>>(
            bufs[L & 1], rowbeg, rowend, part, convW + L * HID * HID,
            convB + L * HID, lnG + L * HID, lnB + L * HID, bufs[(L + 1) & 1]);
    }
    const float* hfin = bufs[N_LAYERS & 1];               // hB after 3 layers

    k_pool2<<<N_GRAPHS * NSLICE, 256, 0, stream>>>(hfin, start, sums, maxs);
    k_mlp<<<N_GRAPHS, 64, 0, stream>>>(sums, maxs, start, W1, b1, W2, b2, out);
}

// Round 11
// 284.447 us; speedup vs baseline: 5.8667x; 1.0745x over previous
//
#include <hip/hip_runtime.h>

#define N_NODES 50000
#define N_EDGES 1250000
#define HID 64
#define N_LAYERS 3
#define N_GRAPHS 64
#define EPS 1e-5f

// ---- dst-partitioned CSR build ----
#define P_SHIFT 7
#define P_NODES 128                                     // nodes per partition
#define NP ((N_NODES + P_NODES - 1) / P_NODES)          // 391
#define PCAP 4096                                       // slots (mean 3200, +16 sigma)

#define LB_NODES 8                                      // nodes per k_layer block

// ---------------- embed gather: h0[i][:] = emb[x[i]][:] (float4) ------------
__global__ __launch_bounds__(256) void k_embed(const int* __restrict__ x,
                                               const float4* __restrict__ emb4,
                                               float4* __restrict__ h4) {
    int i = blockIdx.x * 256 + threadIdx.x;           // over N_NODES * 16
    if (i < N_NODES * 16) {
        int row = i >> 4, q = i & 15;
        h4[i] = emb4[x[row] * 16 + q];
    }
}

// ---- partition edges by dst>>7; per-block contiguous runs (low write-amp) --
__global__ __launch_bounds__(1024) void k_part(const int* __restrict__ src,
                                               const int* __restrict__ dst,
                                               const float* __restrict__ w,
                                               int* __restrict__ pcnt,
                                               int2* __restrict__ part) {
    __shared__ int hist[NP];   // counts, then block base
    __shared__ int cur[NP];
    int t = threadIdx.x;
    for (int k = t; k < NP; k += 1024) { hist[k] = 0; cur[k] = 0; }
    __syncthreads();
    int chunk = (N_EDGES + gridDim.x - 1) / gridDim.x;
    int e0 = blockIdx.x * chunk;
    int e1 = min(e0 + chunk, N_EDGES);
    for (int e = e0 + t; e < e1; e += 1024)
        atomicAdd(&hist[dst[e] >> P_SHIFT], 1);
    __syncthreads();
    for (int k = t; k < NP; k += 1024) {
        int c = hist[k];
        hist[k] = c ? atomicAdd(&pcnt[k], c) : 0;      // reserve block range
    }
    __syncthreads();
    for (int e = e0 + t; e < e1; e += 1024) {
        int d = dst[e];
        int b = d >> P_SHIFT;
        int r = atomicAdd(&cur[b], 1);
        part[(b << 12) + hist[b] + r] =                // PCAP == 4096
            make_int2(((d & (P_NODES - 1)) << 16) | src[e], __float_as_int(w[e]));
    }
}

// ---- per-partition LDS counting sort -> per-node-contiguous CSR (in place) -
// block 0 also computes graph bounds + zeroes pooling scratch
__global__ __launch_bounds__(512) void k_sort(int2* __restrict__ part,
                                              const int* __restrict__ pcnt,
                                              int* __restrict__ rowbeg,
                                              int* __restrict__ rowend,
                                              const int* __restrict__ batch,
                                              int* __restrict__ start,
                                              float* __restrict__ sums,
                                              unsigned* __restrict__ maxs) {
    __shared__ int2 sbuf[PCAP];        // 32 KB
    __shared__ int cnt[P_NODES], base[P_NODES], cur[P_NODES];
    int p = blockIdx.x, t = threadIdx.x;
    if (t < P_NODES) cnt[t] = 0;
    __syncthreads();
    int n = pcnt[p];
    if (n > PCAP) n = PCAP;
    int2* pb = part + (p << 12);
    for (int i = t; i < n; i += 512) atomicAdd(&cnt[pb[i].x >> 16], 1);
    __syncthreads();
    if (t < P_NODES) base[t] = cnt[t];
    __syncthreads();
    for (int off = 1; off < P_NODES; off <<= 1) {
        int v = (t < P_NODES && t >= off) ? base[t - off] : 0;
        __syncthreads();
        if (t < P_NODES) base[t] += v;                 // inclusive scan
        __syncthreads();
    }
    if (t < P_NODES) cur[t] = base[t] - cnt[t];        // exclusive start
    __syncthreads();
    for (int i = t; i < n; i += 512) {
        int2 e = pb[i];
        int pos = atomicAdd(&cur[e.x >> 16], 1);
        sbuf[pos] = e;
    }
    __syncthreads();
    for (int i = t; i < n; i += 512) pb[i] = sbuf[i];  // streaming write-back
    if (t < P_NODES) {
        int node = p * P_NODES + t;
        if (node < N_NODES) {
            rowbeg[node] = (p << 12) + base[t] - cnt[t];
            rowend[node] = (p << 12) + base[t];
        }
    }
    if (p == 0) {                                      // fused misc work
        if (t <= N_GRAPHS) {
            int lo = 0, hi = N_NODES;
            while (lo < hi) {
                int mid = (lo + hi) >> 1;
                if (batch[mid] < t) lo = mid + 1; else hi = mid;
            }
            start[t] = lo;
        }
        for (int k = t; k < N_GRAPHS * HID; k += 512) {
            sums[k] = 0.f;
            maxs[k] = 0u;
        }
    }
}

// ---- fused layer: quad-gather aggregate -> @W -> bias+LN+ReLU --------------
// 512 thr = 8 waves; wave = one node.
// Gather phase: lane = (edge-group g = lane>>4, channel-quad c4 = lane&15);
// one global_load_dwordx4 fetches 4 DIFFERENT src rows per instruction.
// Matvec/LN phase: lane = single channel (round-10 proven path).
__global__ __launch_bounds__(512) void k_layer(const float4* __restrict__ h4,
                                               const int* __restrict__ rowbeg,
                                               const int* __restrict__ rowend,
                                               const int2* __restrict__ csr,
                                               const float* __restrict__ W,
                                               const float* __restrict__ bias,
                                               const float* __restrict__ g,
                                               const float* __restrict__ b,
                                               float* __restrict__ hout) {
    __shared__ float Wl[HID * HID];           // 16 KB
    __shared__ float4 aggl4[LB_NODES][16];    // 2 KB
    int tid = threadIdx.x;
    for (int k = tid; k < HID * HID; k += 512) Wl[k] = W[k];
    __syncthreads();
    int wv = tid >> 6, lane = tid & 63;
    int grp = lane >> 4, c4 = lane & 15;
    int row = blockIdx.x * LB_NODES + wv;     // 50000 % 8 == 0 -> exact
    int p0 = __builtin_amdgcn_readfirstlane(rowbeg[row]);
    int p1 = __builtin_amdgcn_readfirstlane(rowend[row]);
    int last = p1 - 1;
    float4 a0 = make_float4(0.f, 0.f, 0.f, 0.f);
    float4 a1 = a0, a2 = a0, a3 = a0;
    for (int p = p0; p < p1; p += 16) {       // 16 edges per iter, 4 quads
        int i0 = p + grp, i1 = i0 + 4, i2 = i0 + 8, i3 = i0 + 12;
        int2 e0 = csr[min(i0, last)];
        int2 e1 = csr[min(i1, last)];
        int2 e2 = csr[min(i2, last)];
        int2 e3 = csr[min(i3, last)];
        float w0 = (i0 <= last) ? __int_as_float(e0.y) : 0.f;
        float w1 = (i1 <= last) ? __int_as_float(e1.y) : 0.f;
        float w2 = (i2 <= last) ? __int_as_float(e2.y) : 0.f;
        float w3 = (i3 <= last) ? __int_as_float(e3.y) : 0.f;
        float4 v0 = h4[(e0.x & 0xFFFF) * 16 + c4];
        float4 v1 = h4[(e1.x & 0xFFFF) * 16 + c4];
        float4 v2 = h4[(e2.x & 0xFFFF) * 16 + c4];
        float4 v3 = h4[(e3.x & 0xFFFF) * 16 + c4];
        a0.x += v0.x * w0; a0.y += v0.y * w0; a0.z += v0.z * w0; a0.w += v0.w * w0;
        a1.x += v1.x * w1; a1.y += v1.y * w1; a1.z += v1.z * w1; a1.w += v1.w * w1;
        a2.x += v2.x * w2; a2.y += v2.y * w2; a2.z += v2.z * w2; a2.w += v2.w * w2;
        a3.x += v3.x * w3; a3.y += v3.y * w3; a3.z += v3.z * w3; a3.w += v3.w * w3;
    }
    float4 acc;
    acc.x = (a0.x + a1.x) + (a2.x + a3.x);
    acc.y = (a0.y + a1.y) + (a2.y + a3.y);
    acc.z = (a0.z + a1.z) + (a2.z + a3.z);
    acc.w = (a0.w + a1.w) + (a2.w + a3.w);
    // fold the 4 edge-groups (lanes c4, c4+16, c4+32, c4+48 hold partials)
    acc.x += __shfl_xor(acc.x, 16, 64); acc.y += __shfl_xor(acc.y, 16, 64);
    acc.z += __shfl_xor(acc.z, 16, 64); acc.w += __shfl_xor(acc.w, 16, 64);
    acc.x += __shfl_xor(acc.x, 32, 64); acc.y += __shfl_xor(acc.y, 32, 64);
    acc.z += __shfl_xor(acc.z, 32, 64); acc.w += __shfl_xor(acc.w, 32, 64);
    if (grp == 0) aggl4[wv][c4] = acc;        // full agg row -> LDS (per-wave)
    // ---- dense transform (per-wave matvec, 1 channel/lane) ----
    const float* aggl = (const float*)&aggl4[wv][0];
    int j = lane;
    float mv = 0.f;
#pragma unroll 16
    for (int k = 0; k < HID; ++k) mv += aggl[k] * Wl[k * HID + j];
    float v = mv + bias[j];
    float s = v;
#pragma unroll
    for (int off = 32; off; off >>= 1) s += __shfl_xor(s, off, 64);
    float mu = s * (1.f / 64.f);
    float d = v - mu;
    float vv = d * d;
#pragma unroll
    for (int off = 32; off; off >>= 1) vv += __shfl_xor(vv, off, 64);
    float var = vv * (1.f / 64.f);
    float y = d * rsqrtf(var + EPS) * g[j] + b[j];
    hout[row * HID + j] = fmaxf(y, 0.f);
}

// ---------------- pooling: sliced segmented reduction -----------------------
#define NSLICE 16
__global__ __launch_bounds__(256) void k_pool2(const float* __restrict__ h,
                                               const int* __restrict__ start,
                                               float* __restrict__ sums,
                                               unsigned* __restrict__ maxs) {
    int gph = blockIdx.x >> 4;          // / NSLICE
    int sl  = blockIdx.x & (NSLICE - 1);
    int s = start[gph], e1 = start[gph + 1];
    int len = e1 - s;
    int chunk = (len + NSLICE - 1) / NSLICE;
    int r0 = s + sl * chunk;
    int r1 = min(r0 + chunk, e1);
    int j = threadIdx.x & 63, wv = threadIdx.x >> 6;
    float sm = 0.f, mx = 0.f;           // post-ReLU values >= 0
    for (int r = r0 + wv; r < r1; r += 4) {
        float v = h[r * HID + j];
        sm += v;
        mx = fmaxf(mx, v);
    }
    atomicAdd(&sums[gph * HID + j], sm);
    atomicMax(&maxs[gph * HID + j], __float_as_uint(mx));
}

// ---------------- final MLP: relu([mean,max] @ W1 + b1) @ W2 + b2 -----------
__global__ __launch_bounds__(64) void k_mlp(const float* __restrict__ sums,
                                            const unsigned* __restrict__ maxs,
                                            const int* __restrict__ start,
                                            const float* __restrict__ W1,
                                            const float* __restrict__ b1,
                                            const float* __restrict__ W2,
                                            const float* __restrict__ b2,
                                            float* __restrict__ out) {
    int gph = blockIdx.x;
    int j = threadIdx.x;          // 64 threads
    __shared__ float gv[2 * HID];
    int cnt = start[gph + 1] - start[gph];
    float inv = 1.f / fmaxf((float)cnt, 1.f);
    gv[j] = sums[gph * HID + j] * inv;
    float mx = __uint_as_float(maxs[gph * HID + j]);
    gv[HID + j] = (cnt > 0) ? mx : 0.f;
    __syncthreads();
    float acc = b1[j];
#pragma unroll
    for (int k = 0; k < 2 * HID; ++k) acc += gv[k] * W1[k * HID + j];
    acc = fmaxf(acc, 0.f);
    float p = acc * W2[j];
#pragma unroll
    for (int off = 32; off; off >>= 1) p += __shfl_xor(p, off, 64);
    if (j == 0) out[gph] = p + b2[0];
}

extern "C" void kernel_launch(void* const* d_in, const int* in_sizes, int n_in,
                              void* d_out, int out_size, void* d_ws, size_t ws_size,
                              hipStream_t stream) {
    const int*   x     = (const int*)d_in[0];
    const int*   ei    = (const int*)d_in[1];
    const float* ew    = (const float*)d_in[2];
    const int*   batch = (const int*)d_in[3];
    const float* emb   = (const float*)d_in[4];
    const float* convW = (const float*)d_in[5];
    const float* convB = (const float*)d_in[6];
    const float* lnG   = (const float*)d_in[7];
    const float* lnB   = (const float*)d_in[8];
    const float* W1    = (const float*)d_in[9];
    const float* b1    = (const float*)d_in[10];
    const float* W2    = (const float*)d_in[11];
    const float* b2    = (const float*)d_in[12];
    float* out = (float*)d_out;

    // ---- workspace layout (~39 MB) ----
    float* hA     = (float*)d_ws;                         // 12.8 MB
    float* hB     = hA + (size_t)N_NODES * HID;           // 12.8 MB
    int2*  part   = (int2*)(hB + (size_t)N_NODES * HID);  // 12.81 MB (CSR)
    int*   pcnt   = (int*)(part + (size_t)NP * PCAP);     // 391
    int*   rowbeg = pcnt + NP;                            // 50000
    int*   rowend = rowbeg + N_NODES;                     // 50000
    float* sums   = (float*)(rowend + N_NODES);           // 4096
    unsigned* maxs = (unsigned*)(sums + N_GRAPHS * HID);  // 4096
    int*   start  = (int*)(maxs + N_GRAPHS * HID);        // 65

    const int* src = ei;
    const int* dst = ei + N_EDGES;

    hipMemsetAsync(pcnt, 0, NP * sizeof(int), stream);
    k_part<<<256, 1024, 0, stream>>>(src, dst, ew, pcnt, part);
    k_sort<<<NP, 512, 0, stream>>>(part, pcnt, rowbeg, rowend,
                                   batch, start, sums, maxs);
    k_embed<<<(N_NODES * 16 + 255) / 256, 256, 0, stream>>>(
        x, (const float4*)emb, (float4*)hA);

    float* bufs[2] = { hA, hB };
    for (int L = 0; L < N_LAYERS; ++L) {
        k_layer<<<N_NODES / LB_NODES, 512, 0, stream>>>(
            (const float4*)bufs[L & 1], rowbeg, rowend, part,
            convW + L * HID * HID, convB + L * HID,
            lnG + L * HID, lnB + L * HID, bufs[(L + 1) & 1]);
    }
    const float* hfin = bufs[N_LAYERS & 1];               // hB after 3 layers

    k_pool2<<<N_GRAPHS * NSLICE, 256, 0, stream>>>(hfin, start, sums, maxs);
    k_mlp<<<N_GRAPHS, 64, 0, stream>>>(sums, maxs, start, W1, b1, W2, b2, out);
}